// Round 11
// baseline (519.110 us; speedup 1.0000x reference)
//
#include <hip/hip_runtime.h>
#include <hip/hip_bf16.h>

typedef __bf16 bf16;
typedef __bf16 bf16x8 __attribute__((ext_vector_type(8)));
typedef __bf16 bf16x4 __attribute__((ext_vector_type(4)));
typedef float  f32x4  __attribute__((ext_vector_type(4)));

#define GLD16(g, l) __builtin_amdgcn_global_load_lds(                        \
    (const __attribute__((address_space(1))) void*)(g),                      \
    (__attribute__((address_space(3))) void*)(l), 16, 0, 0)

// ---------------------------------------------------------------------------
// NT GEMM: C[m,n] = alpha * sum_k A[m,k]*B[n,k] (+ bias[n]) (+ relu) (+ res)
// BK=64; swizzled LDS (conflict-free, R2); pointer-bump staging (R3).
// Tile rule (R7/R8): BM=128 throughput-bound, BM=64 latency-bound short grids.
// vt != nullptr (R11): n-tiles in [1536,2304) additionally emit V^T via an
// LDS round-trip (stride BM+4 => conflict-free) with COALESCED 16B stores —
// fixes R4's uncoalesced-fusion failure (8B stores @1024B stride, 2x write amp).
// ---------------------------------------------------------------------------
template<int BM, int BN, int MFR, int NFR>
__global__ __launch_bounds__(256, 3)
void gemm_nt(const bf16* __restrict__ A, const bf16* __restrict__ B,
             bf16* __restrict__ C, const float* __restrict__ bias,
             int K, int lda, int ldb, int ldc,
             int inner,
             long long aOut, long long aIn,
             long long bOut, long long bIn,
             long long cOut, long long cIn,
             float alpha, int relu,
             const bf16* __restrict__ res, int ldr,
             bf16* __restrict__ vt)
{
    const int z  = blockIdx.z;
    const int zo = z / inner;
    const int zi = z - zo * inner;
    A += (long long)zo * aOut + (long long)zi * aIn;
    B += (long long)zo * bOut + (long long)zi * bIn;
    C += (long long)zo * cOut + (long long)zi * cIn;

    const int tm = blockIdx.y * BM;
    const int tn = blockIdx.x * BN;

    constexpr int SM1 = (BM + BN) * 64;
    constexpr int SM2 = BN * (BM + 4);
    __shared__ __align__(16) bf16 smem[SM1 > SM2 ? SM1 : SM2];
    bf16* As = smem;
    bf16* Bs = smem + BM * 64;

    const int tid  = threadIdx.x;
    const int lane = tid & 63;
    const int wid  = tid >> 6;
    const int wr   = wid >> 1;
    const int wc   = wid & 1;

    f32x4 acc[MFR][NFR];
#pragma unroll
    for (int i = 0; i < MFR; ++i)
#pragma unroll
        for (int j = 0; j < NFR; ++j) acc[i][j] = (f32x4){0.f, 0.f, 0.f, 0.f};

    const int srow = lane >> 3;
    const int gch8 = ((lane & 7) ^ srow) * 8;

    const int NA = BM / 32;
    const int NB = BN / 32;

    const bf16* aP[NA];
#pragma unroll
    for (int jj = 0; jj < NA; ++jj) {
        const int R0 = (wid * NA + jj) * 8;
        aP[jj] = A + (long long)(tm + R0 + srow) * lda + gch8;
    }
    const bf16* bP[NB];
#pragma unroll
    for (int jj = 0; jj < NB; ++jj) {
        const int R0 = (wid * NB + jj) * 8;
        bP[jj] = B + (long long)(tn + R0 + srow) * ldb + gch8;
    }

    const int lr = lane & 15;
    const int qg = lane >> 4;

    for (int kt = 0; kt < K; kt += 64) {
#pragma unroll
        for (int jj = 0; jj < NA; ++jj)
            GLD16(aP[jj], As + (wid * NA + jj) * 512);
#pragma unroll
        for (int jj = 0; jj < NB; ++jj)
            GLD16(bP[jj], Bs + (wid * NB + jj) * 512);
        __syncthreads();

#pragma unroll
        for (int h = 0; h < 2; ++h) {
            const int off = ((qg + h * 4) ^ (lr & 7)) * 8;
            bf16x8 af[MFR], bfr[NFR];
#pragma unroll
            for (int i = 0; i < MFR; ++i)
                af[i] = *(const bf16x8*)(As + (wr * MFR * 16 + i * 16 + lr) * 64 + off);
#pragma unroll
            for (int j = 0; j < NFR; ++j)
                bfr[j] = *(const bf16x8*)(Bs + (wc * NFR * 16 + j * 16 + lr) * 64 + off);
#pragma unroll
            for (int i = 0; i < MFR; ++i)
#pragma unroll
                for (int j = 0; j < NFR; ++j)
                    acc[i][j] = __builtin_amdgcn_mfma_f32_16x16x32_bf16(
                        af[i], bfr[j], acc[i][j], 0, 0, 0);
        }
        __syncthreads();
#pragma unroll
        for (int jj = 0; jj < NA; ++jj) aP[jj] += 64;
#pragma unroll
        for (int jj = 0; jj < NB; ++jj) bP[jj] += 64;
    }

    const bool do_vt = (vt != nullptr) && (tn >= 1536) && (tn < 2304);

#pragma unroll
    for (int i = 0; i < MFR; ++i) {
#pragma unroll
        for (int j = 0; j < NFR; ++j) {
            const int mm0 = tm + wr * MFR * 16 + i * 16 + (lane >> 4) * 4;
            const int nn  = tn + wc * NFR * 16 + j * 16 + (lane & 15);
#pragma unroll
            for (int r = 0; r < 4; ++r) {
                float v = acc[i][j][r] * alpha;
                if (bias) v += bias[nn];
                if (res)  v += (float)res[(long long)(mm0 + r) * ldr + nn];
                if (relu) v = fmaxf(v, 0.f);
                C[(long long)(mm0 + r) * ldc + nn] = (bf16)v;
                if (do_vt)
                    smem[(nn - tn) * (BM + 4) + (mm0 + r - tm)] = (bf16)v;
            }
        }
    }

    if (do_vt) {
        // copy transposed tile to VT with coalesced 16B stores.
        __syncthreads();
        const int s0 = tm & 511;
        const int bb = tm >> 9;
#pragma unroll
        for (int k2 = 0; k2 < (BM * BN / 8) / 256; ++k2) {
            const int c   = k2 * 256 + tid;
            const int row = c >> 4;           // n-local 0..BN-1
            const int ch  = c & 15;           // 16B chunk along m
            const int t   = tn - 1536 + row;
            const int hh  = t / 192;
            const int hd  = t - hh * 192;
            const bf16x8 v8 = *(const bf16x8*)(smem + row * (BM + 4) + ch * 8);
            *(bf16x8*)(vt + ((long long)((bb << 2) + hh) * 192 + hd) * 512
                       + s0 + ch * 8) = v8;
        }
    }
}

// ---------------------------------------------------------------------------
// Fused flash-style attention (R6-verified; R7 XCD-aware grid swizzle).
// ---------------------------------------------------------------------------
__global__ __launch_bounds__(256, 2)
void fused_attn_kernel(bf16* __restrict__ qkvx, const bf16* __restrict__ vt)
{
    const int flat = blockIdx.x;                     // 0..511
    const int qt = (flat >> 3) & 3;                  // q-tile
    const int z  = (flat & 7) | ((flat >> 5) << 3);  // b*4 + h
    const int b  = z >> 2, h = z & 3;

    const bf16* Qg  = qkvx + (long long)b * 512 * 3072 + h * 192;
    const bf16* Kg  = qkvx + (long long)b * 512 * 3072 + 768 + h * 192;
    const bf16* VTg = vt + (long long)z * 192 * 512;

    __shared__ __align__(16) bf16 Ks[64 * 192];    // [key][d], 24ch rows, XOR-swz
    __shared__ __align__(16) bf16 VTs[192 * 64];   // [d][key], 8ch rows, XOR-swz
    __shared__ __align__(16) bf16 Pb[4 * 32 * 64]; // per-wave [m][key], XOR-swz

    const int tid  = threadIdx.x;
    const int lane = tid & 63;
    const int wid  = tid >> 6;
    const int lr   = lane & 15;
    const int qg   = lane >> 4;
    const int m0   = qt * 128 + wid * 32;

    bf16x8 qf[2][6];
#pragma unroll
    for (int mt = 0; mt < 2; ++mt)
#pragma unroll
        for (int t = 0; t < 6; ++t)
            qf[mt][t] = *(const bf16x8*)(Qg + (long long)(m0 + mt * 16 + lr) * 3072
                                         + t * 32 + qg * 8);

    const bf16* kP[6];
    const bf16* vP[6];
#pragma unroll
    for (int i = 0; i < 6; ++i) {
        const int c = i * 256 + tid;
        const int krow = c / 24, kcc = c % 24;
        const int kgc  = (kcc & 24) | ((kcc & 7) ^ (krow & 7));
        kP[i] = Kg + (long long)krow * 3072 + kgc * 8;
        const int vrow = c >> 3, vcc = c & 7;
        const int vgc  = vcc ^ (vrow & 7);
        vP[i] = VTg + (long long)vrow * 512 + vgc * 8;
    }

    f32x4 acc[2][12];
#pragma unroll
    for (int mt = 0; mt < 2; ++mt)
#pragma unroll
        for (int dt = 0; dt < 12; ++dt) acc[mt][dt] = (f32x4){0.f, 0.f, 0.f, 0.f};
    float mrow[2][4], lrow[2][4];
#pragma unroll
    for (int mt = 0; mt < 2; ++mt)
#pragma unroll
        for (int r = 0; r < 4; ++r) { mrow[mt][r] = -3e38f; lrow[mt][r] = 0.f; }

    const float alpha = 0.0721687836f;   // 1/sqrt(192)

    for (int kt = 0; kt < 8; ++kt) {
#pragma unroll
        for (int i = 0; i < 6; ++i)
            GLD16(kP[i], Ks + (i * 256 + wid * 64) * 8);
#pragma unroll
        for (int i = 0; i < 6; ++i)
            GLD16(vP[i], VTs + (i * 256 + wid * 64) * 8);
        __syncthreads();

        f32x4 sf[2][4];
#pragma unroll
        for (int mt = 0; mt < 2; ++mt)
#pragma unroll
            for (int nt = 0; nt < 4; ++nt) sf[mt][nt] = (f32x4){0.f, 0.f, 0.f, 0.f};
#pragma unroll
        for (int nt = 0; nt < 4; ++nt) {
#pragma unroll
            for (int t = 0; t < 6; ++t) {
                const int ch = t * 4 + qg;
                const int ph = (ch & 24) | ((ch & 7) ^ (lr & 7));
                const bf16x8 kf = *(const bf16x8*)(Ks + (nt * 16 + lr) * 192 + ph * 8);
                sf[0][nt] = __builtin_amdgcn_mfma_f32_16x16x32_bf16(qf[0][t], kf, sf[0][nt], 0, 0, 0);
                sf[1][nt] = __builtin_amdgcn_mfma_f32_16x16x32_bf16(qf[1][t], kf, sf[1][nt], 0, 0, 0);
            }
        }

#pragma unroll
        for (int mt = 0; mt < 2; ++mt) {
            float mx[4], a[4], rs[4], p[4][4];
#pragma unroll
            for (int r = 0; r < 4; ++r) {
                float v0 = fmaxf(sf[mt][0][r], sf[mt][1][r]);
                float v1 = fmaxf(sf[mt][2][r], sf[mt][3][r]);
                mx[r] = fmaxf(v0, v1) * alpha;
            }
#pragma unroll
            for (int msk = 1; msk <= 8; msk <<= 1)
#pragma unroll
                for (int r = 0; r < 4; ++r) mx[r] = fmaxf(mx[r], __shfl_xor(mx[r], msk));
#pragma unroll
            for (int r = 0; r < 4; ++r) {
                const float mn = fmaxf(mrow[mt][r], mx[r]);
                a[r] = __expf(mrow[mt][r] - mn);
                mrow[mt][r] = mn;
                rs[r] = 0.f;
            }
#pragma unroll
            for (int nt = 0; nt < 4; ++nt)
#pragma unroll
                for (int r = 0; r < 4; ++r) {
                    p[nt][r] = __expf(sf[mt][nt][r] * alpha - mrow[mt][r]);
                    rs[r] += p[nt][r];
                }
#pragma unroll
            for (int msk = 1; msk <= 8; msk <<= 1)
#pragma unroll
                for (int r = 0; r < 4; ++r) rs[r] += __shfl_xor(rs[r], msk);
#pragma unroll
            for (int r = 0; r < 4; ++r) lrow[mt][r] = lrow[mt][r] * a[r] + rs[r];
#pragma unroll
            for (int dt = 0; dt < 12; ++dt)
#pragma unroll
                for (int r = 0; r < 4; ++r) acc[mt][dt][r] *= a[r];
#pragma unroll
            for (int nt = 0; nt < 4; ++nt)
#pragma unroll
                for (int r = 0; r < 4; ++r) {
                    const int row = mt * 16 + qg * 4 + r;
                    const int ph2 = (nt * 2 + (lr >> 3)) ^ (row & 7);
                    Pb[wid * 2048 + row * 64 + ph2 * 8 + (lr & 7)] = (bf16)p[nt][r];
                }
        }

        bf16x8 pf[2][2];
#pragma unroll
        for (int mt = 0; mt < 2; ++mt)
#pragma unroll
            for (int ks = 0; ks < 2; ++ks) {
                const int row = mt * 16 + lr;
                const int ph  = (ks * 4 + qg) ^ (lr & 7);
                pf[mt][ks] = *(const bf16x8*)(Pb + wid * 2048 + row * 64 + ph * 8);
            }
#pragma unroll
        for (int dt = 0; dt < 12; ++dt) {
#pragma unroll
            for (int ks = 0; ks < 2; ++ks) {
                const int ph = (ks * 4 + qg) ^ (lr & 7);
                const bf16x8 vf = *(const bf16x8*)(VTs + (dt * 16 + lr) * 64 + ph * 8);
                acc[0][dt] = __builtin_amdgcn_mfma_f32_16x16x32_bf16(pf[0][ks], vf, acc[0][dt], 0, 0, 0);
                acc[1][dt] = __builtin_amdgcn_mfma_f32_16x16x32_bf16(pf[1][ks], vf, acc[1][dt], 0, 0, 0);
            }
        }
        __syncthreads();
#pragma unroll
        for (int i = 0; i < 6; ++i) { kP[i] += 64 * 3072; vP[i] += 64; }
    }

    bf16* Og = qkvx + (long long)b * 512 * 3072 + h * 192;
#pragma unroll
    for (int mt = 0; mt < 2; ++mt) {
        float inv[4];
#pragma unroll
        for (int r = 0; r < 4; ++r) inv[r] = 1.0f / lrow[mt][r];
#pragma unroll
        for (int dt = 0; dt < 12; ++dt)
#pragma unroll
            for (int r = 0; r < 4; ++r) {
                const int row = m0 + mt * 16 + qg * 4 + r;
                Og[(long long)row * 3072 + dt * 16 + lr] = (bf16)(acc[mt][dt][r] * inv[r]);
            }
    }
}

// ---------------------------------------------------------------------------
// one-shot prep kernel: weight casts/transposes + fused bias + x+PE cast.
// ---------------------------------------------------------------------------
__device__ __forceinline__ void cast4(const float* src, bf16* dst, int i)
{
    const float4 v = *(const float4*)(src + (long long)i * 4);
    bf16x4 o;
    o[0] = (bf16)v.x; o[1] = (bf16)v.y; o[2] = (bf16)v.z; o[3] = (bf16)v.w;
    *(bf16x4*)(dst + (long long)i * 4) = o;
}

__global__ __launch_bounds__(256)
void prep_kernel(const float* __restrict__ wq, const float* __restrict__ wk,
                 const float* __restrict__ wv, const float* __restrict__ wx,
                 const float* __restrict__ inpw, const float* __restrict__ inpb,
                 const float* __restrict__ bq, const float* __restrict__ bk,
                 const float* __restrict__ bv, const float* __restrict__ bx,
                 const float* __restrict__ woutp, const float* __restrict__ wf1a,
                 const float* __restrict__ wf1b, const float* __restrict__ x,
                 bf16* __restrict__ WT3, bf16* __restrict__ INPJ,
                 bf16* __restrict__ WOUT, bf16* __restrict__ WF1A,
                 bf16* __restrict__ WF1B, bf16* __restrict__ WXD,
                 float* __restrict__ BCAT, bf16* __restrict__ XPE)
{
    const int blk = blockIdx.x;
    const int tid = threadIdx.x;
    __shared__ bf16 t[32][33];

    if (blk < 1728) {
        const int which = blk / 576, local = blk - which * 576;
        const float* src = (which == 0) ? wq : ((which == 1) ? wk : wv);
        bf16* dst = WT3 + (long long)which * 589824;
        const int r0 = (local / 24) * 32, c0 = (local % 24) * 32;
        const int tr = tid >> 5, tc = tid & 31;
#pragma unroll
        for (int k = 0; k < 4; ++k) {
            const int r = tr + k * 8;
            t[r][tc] = (bf16)src[(long long)(r0 + r) * 768 + c0 + tc];
        }
        __syncthreads();
#pragma unroll
        for (int k = 0; k < 4; ++k) {
            const int c = tr + k * 8;
            dst[(long long)(c0 + c) * 768 + r0 + tc] = t[tc][c];
        }
    } else if (blk < 3456) {
        cast4(inpw, INPJ, (blk - 1728) * 256 + tid);
    } else if (blk < 4032) {
        cast4(woutp, WOUT, (blk - 3456) * 256 + tid);
    } else if (blk < 4608) {
        cast4(wf1a, WF1A, (blk - 4032) * 256 + tid);
    } else if (blk < 5184) {
        cast4(wf1b, WF1B, (blk - 4608) * 256 + tid);
    } else if (blk < 5760) {
        cast4(wx, WXD, (blk - 5184) * 256 + tid);
    } else if (blk < 6051) {
        const int bl = blk - 5760;
        if (bl < 288) {
            const int g = tid >> 5, l = tid & 31;
            const int n = bl * 8 + g;
            const int zsec = n / 768;
            const float* bb = (zsec == 0) ? bq : ((zsec == 1) ? bk : bv);
            const float* wrow = inpw + (long long)n * 768;
            float s = 0.f;
            for (int d = l; d < 768; d += 32) s += wrow[d] * bb[d];
#pragma unroll
            for (int off = 16; off; off >>= 1) s += __shfl_xor(s, off);
            if (l == 0) BCAT[n] = inpb[n] + s;
        } else {
            const int n = (bl - 288) * 256 + tid;
            if (n < 768) BCAT[2304 + n] = bx[n];
        }
    } else {
        const int idx4 = ((blk - 6051) * 256 + tid) * 4;
        const int d    = idx4 % 768;
        const int row  = idx4 / 768;
        const int s    = row & 511;
        const float ksc = -0.034603417655076f;  // -2*log2(10000)/768
        const float4 xv = *(const float4*)(x + (long long)idx4);
        float a0 = (float)s * exp2f((float)d * ksc);
        float a1 = (float)s * exp2f((float)(d + 2) * ksc);
        float s0, c0, s1, c1;
        sincosf(a0, &s0, &c0);
        sincosf(a1, &s1, &c1);
        bf16x4 o;
        o[0] = (bf16)(xv.x + s0);
        o[1] = (bf16)(xv.y + c0);
        o[2] = (bf16)(xv.z + s1);
        o[3] = (bf16)(xv.w + c1);
        *(bf16x4*)(XPE + (long long)idx4) = o;
    }
}

// LayerNorm of one (pre-summed) row -> o.  192 threads, bf16x4.
__global__ __launch_bounds__(192)
void ln1_kernel(const bf16* __restrict__ a, int lda_,
                bf16* __restrict__ o, int ldo,
                const float* __restrict__ g, const float* __restrict__ be)
{
    const int row = blockIdx.x;
    const int t   = threadIdx.x;
    const int d0  = t * 4;
    const bf16x4 av = *(const bf16x4*)(a + (long long)row * lda_ + d0);
    float xv[4];
#pragma unroll
    for (int k = 0; k < 4; ++k) xv[k] = (float)av[k];
    float s1 = xv[0] + xv[1] + xv[2] + xv[3];
    float s2 = xv[0]*xv[0] + xv[1]*xv[1] + xv[2]*xv[2] + xv[3]*xv[3];
    for (int off = 32; off; off >>= 1) {
        s1 += __shfl_xor(s1, off);
        s2 += __shfl_xor(s2, off);
    }
    __shared__ float red[6];
    const int wid = t >> 6, lane = t & 63;
    if (lane == 0) { red[wid] = s1; red[3 + wid] = s2; }
    __syncthreads();
    s1 = red[0] + red[1] + red[2];
    s2 = red[3] + red[4] + red[5];
    const float mu  = s1 * (1.0f / 768.0f);
    const float var = s2 * (1.0f / 768.0f) - mu * mu;
    const float rs  = rsqrtf(var + 1e-5f);
    const float4 gv = *(const float4*)(g + d0);
    const float4 ev = *(const float4*)(be + d0);
    bf16x4 ov;
    ov[0] = (bf16)(((xv[0] - mu) * rs) * gv.x + ev.x);
    ov[1] = (bf16)(((xv[1] - mu) * rs) * gv.y + ev.y);
    ov[2] = (bf16)(((xv[2] - mu) * rs) * gv.z + ev.z);
    ov[3] = (bf16)(((xv[3] - mu) * rs) * gv.w + ev.w);
    *(bf16x4*)(o + (long long)row * ldo + d0) = ov;
}

// ---------------------------------------------------------------------------
// LN2 + s-sum + fc2, fully fused (R11).  Wave-parallel LN (R10-verified),
// then each block dots its 768-partial with the 10 fc2 rows and atomicAdds
// into out[b][c] (out pre-zeroed by hipMemsetAsync).  Block blk%16==0 also
// adds the bias.  x2 and the PART buffer never hit HBM.
// ---------------------------------------------------------------------------
__global__ __launch_bounds__(256)
void ln2_fc2_kernel(const bf16* __restrict__ src,  /* ffn+x1, ld 3072 */
                    const float* __restrict__ g, const float* __restrict__ be,
                    const float* __restrict__ w, const float* __restrict__ bias,
                    float* __restrict__ out)
{
    const int blk  = blockIdx.x;          // 0..511 (32 rows each)
    const int b    = blk >> 4;
    const int tid  = threadIdx.x;
    const int wid  = tid >> 6, lane = tid & 63;
    const int d0   = lane * 12;

    float gv[12], ev[12];
#pragma unroll
    for (int k = 0; k < 12; k += 4) {
        *(float4*)(gv + k) = *(const float4*)(g + d0 + k);
        *(float4*)(ev + k) = *(const float4*)(be + d0 + k);
    }
    float acc[12];
#pragma unroll
    for (int k = 0; k < 12; ++k) acc[k] = 0.f;

    for (int i = 0; i < 8; ++i) {
        const int row = blk * 32 + i * 4 + wid;
        const bf16* p = src + (long long)row * 3072 + d0;
        float xv[12];
#pragma unroll
        for (int k = 0; k < 12; k += 4) {
            const bf16x4 v = *(const bf16x4*)(p + k);
            xv[k] = (float)v[0]; xv[k+1] = (float)v[1];
            xv[k+2] = (float)v[2]; xv[k+3] = (float)v[3];
        }
        float s1 = 0.f, s2 = 0.f;
#pragma unroll
        for (int k = 0; k < 12; ++k) { s1 += xv[k]; s2 += xv[k] * xv[k]; }
        for (int off = 32; off; off >>= 1) {
            s1 += __shfl_xor(s1, off);
            s2 += __shfl_xor(s2, off);
        }
        const float mu  = s1 * (1.0f / 768.0f);
        const float var = s2 * (1.0f / 768.0f) - mu * mu;
        const float rs  = rsqrtf(var + 1e-5f);
#pragma unroll
        for (int k = 0; k < 12; ++k) acc[k] += (xv[k] - mu) * rs * gv[k] + ev[k];
    }

    __shared__ float red[4][768];
#pragma unroll
    for (int k = 0; k < 12; k += 4)
        *(float4*)(&red[wid][d0 + k]) = *(const float4*)(acc + k);
    __syncthreads();

    // lane l owns d = l + 64j (j=0..11); total = sum of 4 wave-partials
    float tot[12];
#pragma unroll
    for (int j = 0; j < 12; ++j) {
        const int d = lane + 64 * j;
        tot[j] = red[0][d] + red[1][d] + red[2][d] + red[3][d];
    }
    // wave wid handles classes c = wid, wid+4, wid+8 (<10)
    for (int c = wid; c < 10; c += 4) {
        float s = 0.f;
#pragma unroll
        for (int j = 0; j < 12; ++j) s += tot[j] * w[c * 768 + lane + 64 * j];
        for (int off = 32; off; off >>= 1) s += __shfl_xor(s, off);
        if (lane == 0) {
            if ((blk & 15) == 0) s += bias[c];
            atomicAdd(&out[b * 10 + c], s);
        }
    }
}

// ---------------------------------------------------------------------------
// workspace layout (bytes)
// ---------------------------------------------------------------------------
static const size_t OFF_XPE  = 0;
static const size_t OFF_WCAT = OFF_XPE  + (size_t)16384 * 768 * 2;
static const size_t OFF_WT3  = OFF_WCAT + (size_t)3072 * 768 * 2;
static const size_t OFF_INPJ = OFF_WT3  + (size_t)3 * 768 * 768 * 2;
static const size_t OFF_WOUT = OFF_INPJ + (size_t)2304 * 768 * 2;
static const size_t OFF_WF1A = OFF_WOUT + (size_t)768 * 768 * 2;
static const size_t OFF_WF1B = OFF_WF1A + (size_t)768 * 768 * 2;
static const size_t OFF_BCAT = OFF_WF1B + (size_t)768 * 768 * 2;
static const size_t OFF_QKVX = OFF_BCAT + (size_t)3072 * 4;
static const size_t OFF_VT   = OFF_QKVX + (size_t)16384 * 3072 * 2;
static const size_t OFF_S    = OFF_VT   + (size_t)128 * 192 * 512 * 2;
static const size_t OFF_X1   = OFF_S    + (size_t)128 * 512 * 512 * 2;

extern "C" void kernel_launch(void* const* d_in, const int* in_sizes, int n_in,
                              void* d_out, int out_size, void* d_ws, size_t ws_size,
                              hipStream_t stream)
{
    const float* x     = (const float*)d_in[0];
    const float* wq    = (const float*)d_in[1];
    const float* bq    = (const float*)d_in[2];
    const float* wk    = (const float*)d_in[3];
    const float* bk    = (const float*)d_in[4];
    const float* wv    = (const float*)d_in[5];
    const float* bv    = (const float*)d_in[6];
    const float* wx    = (const float*)d_in[7];
    const float* bx    = (const float*)d_in[8];
    const float* inpw  = (const float*)d_in[9];
    const float* inpb  = (const float*)d_in[10];
    const float* woutp = (const float*)d_in[11];
    const float* boutp = (const float*)d_in[12];
    const float* wf1a  = (const float*)d_in[13];
    const float* bf1a  = (const float*)d_in[14];
    const float* wf1b  = (const float*)d_in[15];
    const float* bf1b  = (const float*)d_in[16];
    const float* lng   = (const float*)d_in[17];
    const float* lnb   = (const float*)d_in[18];
    const float* wfc2  = (const float*)d_in[19];
    const float* bfc2  = (const float*)d_in[20];
    float* out = (float*)d_out;

    char* ws = (char*)d_ws;
    bf16*  XPE  = (bf16*)(ws + OFF_XPE);
    bf16*  WCAT = (bf16*)(ws + OFF_WCAT);
    bf16*  WT3  = (bf16*)(ws + OFF_WT3);
    bf16*  INPJ = (bf16*)(ws + OFF_INPJ);
    bf16*  WOUT = (bf16*)(ws + OFF_WOUT);
    bf16*  WF1A = (bf16*)(ws + OFF_WF1A);
    bf16*  WF1B = (bf16*)(ws + OFF_WF1B);
    float* BCAT = (float*)(ws + OFF_BCAT);
    bf16*  QKVX = (bf16*)(ws + OFF_QKVX);
    bf16*  VT   = (bf16*)(ws + OFF_VT);
    bf16*  X1   = (bf16*)(ws + OFF_X1);

    // zero the (atomically accumulated) output
    hipMemsetAsync(d_out, 0, (size_t)out_size * sizeof(float), stream);

    // ---- prep: weights + bias + x+PE (single dispatch) ----
    prep_kernel<<<18339, 256, 0, stream>>>(wq, wk, wv, wx, inpw, inpb,
                                           bq, bk, bv, bx, woutp, wf1a, wf1b, x,
                                           WT3, INPJ, WOUT, WF1A, WF1B,
                                           WCAT + (size_t)2304 * 768, BCAT, XPE);

    // W_eff[z] = in_proj_w[z] @ w{q,k,v}
    gemm_nt<64, 128, 2, 4><<<dim3(6, 12, 3), 256, 0, stream>>>(
        INPJ, WT3, WCAT, nullptr, 768, 768, 768, 768,
        1, 589824, 0, 589824, 0, 589824, 0, 1.0f, 0, nullptr, 0, nullptr);

    // QKVX = XPE @ WCAT^T + BCAT -> [16384,3072]; V^T emitted fused (coalesced)
    gemm_nt<128, 128, 4, 4><<<dim3(24, 128, 1), 256, 0, stream>>>(
        XPE, WCAT, QKVX, BCAT, 768, 768, 768, 3072,
        1, 0, 0, 0, 0, 0, 0, 1.0f, 0, nullptr, 0, VT);

    // fused attention (XCD-swizzled grid): Q2 region overwritten with ctx
    fused_attn_kernel<<<512, 256, 0, stream>>>(QKVX, VT);

    // attn_out + XR residual -> K2 region  (BM=64: latency-bound)
    gemm_nt<64, 128, 2, 4><<<dim3(6, 256, 1), 256, 0, stream>>>(
        QKVX, WOUT, QKVX + 768, boutp, 768, 3072, 768, 3072,
        1, 0, 0, 0, 0, 0, 0, 1.0f, 0, QKVX + 2304, 3072, nullptr);

    // x1 = LN(attn_out + XR)
    ln1_kernel<<<16384, 192, 0, stream>>>(QKVX + 768, 3072, X1, 768, lng, lnb);

    // h1 = relu(x1 @ fc1a^T + b) -> V2 region
    gemm_nt<64, 128, 2, 4><<<dim3(6, 256, 1), 256, 0, stream>>>(
        X1, WF1A, QKVX + 1536, bf1a, 768, 768, 768, 3072,
        1, 0, 0, 0, 0, 0, 0, 1.0f, 1, nullptr, 0, nullptr);

    // ffn + x1 residual -> XR region
    gemm_nt<64, 128, 2, 4><<<dim3(6, 256, 1), 256, 0, stream>>>(
        QKVX + 1536, WF1B, QKVX + 2304, bf1b, 768, 3072, 768, 3072,
        1, 0, 0, 0, 0, 0, 0, 1.0f, 0, X1, 768, nullptr);

    // LN2 + s-sum + fc2 fused (atomics into zeroed out)
    ln2_fc2_kernel<<<512, 256, 0, stream>>>(QKVX + 2304, lng, lnb,
                                            wfc2, bfc2, out);
}

// Round 12
// 508.658 us; speedup vs baseline: 1.0205x; 1.0205x over previous
//
#include <hip/hip_runtime.h>
#include <hip/hip_bf16.h>

typedef __bf16 bf16;
typedef __bf16 bf16x8 __attribute__((ext_vector_type(8)));
typedef __bf16 bf16x4 __attribute__((ext_vector_type(4)));
typedef float  f32x4  __attribute__((ext_vector_type(4)));

#define GLD16(g, l) __builtin_amdgcn_global_load_lds(                        \
    (const __attribute__((address_space(1))) void*)(g),                      \
    (__attribute__((address_space(3))) void*)(l), 16, 0, 0)

// ---------------------------------------------------------------------------
// NT GEMM: C[m,n] = alpha * sum_k A[m,k]*B[n,k] (+ bias[n]) (+ relu) (+ res)
// BK=64; swizzled LDS (conflict-free, R2); pointer-bump staging (R3).
// Tile rule (R7/R8): BM=128 throughput-bound, BM=64 latency-bound short grids.
// R12: swzN != 0 => flat 1-D grid with XCD-aware tile swizzle: all blocks
// sharing an A m-tile land on one XCD (g&7), so A is fetched into that XCD's
// L2 once instead of 8x (R11 counters: QKVX FETCH 107 MB vs 30 MB ideal).
// ---------------------------------------------------------------------------
template<int BM, int BN, int MFR, int NFR>
__global__ __launch_bounds__(256, 3)
void gemm_nt(const bf16* __restrict__ A, const bf16* __restrict__ B,
             bf16* __restrict__ C, const float* __restrict__ bias,
             int K, int lda, int ldb, int ldc,
             int inner,
             long long aOut, long long aIn,
             long long bOut, long long bIn,
             long long cOut, long long cIn,
             float alpha, int relu,
             const bf16* __restrict__ res, int ldr,
             int swzN)
{
    int tm, tn;
    if (swzN) {
        const int g    = blockIdx.x;
        const int xcd  = g & 7;
        const int slot = g >> 3;
        const int mPer = (int)(gridDim.x >> 3) / swzN;   // m-tiles per XCD
        tm = (xcd * mPer + slot / swzN) * BM;
        tn = (slot % swzN) * BN;
    } else {
        tm = blockIdx.y * BM;
        tn = blockIdx.x * BN;
    }

    const int z  = blockIdx.z;
    const int zo = z / inner;
    const int zi = z - zo * inner;
    A += (long long)zo * aOut + (long long)zi * aIn;
    B += (long long)zo * bOut + (long long)zi * bIn;
    C += (long long)zo * cOut + (long long)zi * cIn;

    __shared__ __align__(16) bf16 smem[(BM + BN) * 64];
    bf16* As = smem;
    bf16* Bs = smem + BM * 64;

    const int tid  = threadIdx.x;
    const int lane = tid & 63;
    const int wid  = tid >> 6;
    const int wr   = wid >> 1;
    const int wc   = wid & 1;

    f32x4 acc[MFR][NFR];
#pragma unroll
    for (int i = 0; i < MFR; ++i)
#pragma unroll
        for (int j = 0; j < NFR; ++j) acc[i][j] = (f32x4){0.f, 0.f, 0.f, 0.f};

    const int srow = lane >> 3;
    const int gch8 = ((lane & 7) ^ srow) * 8;

    const int NA = BM / 32;
    const int NB = BN / 32;

    const bf16* aP[NA];
#pragma unroll
    for (int jj = 0; jj < NA; ++jj) {
        const int R0 = (wid * NA + jj) * 8;
        aP[jj] = A + (long long)(tm + R0 + srow) * lda + gch8;
    }
    const bf16* bP[NB];
#pragma unroll
    for (int jj = 0; jj < NB; ++jj) {
        const int R0 = (wid * NB + jj) * 8;
        bP[jj] = B + (long long)(tn + R0 + srow) * ldb + gch8;
    }

    const int lr = lane & 15;
    const int qg = lane >> 4;

    for (int kt = 0; kt < K; kt += 64) {
#pragma unroll
        for (int jj = 0; jj < NA; ++jj)
            GLD16(aP[jj], As + (wid * NA + jj) * 512);
#pragma unroll
        for (int jj = 0; jj < NB; ++jj)
            GLD16(bP[jj], Bs + (wid * NB + jj) * 512);
        __syncthreads();

#pragma unroll
        for (int h = 0; h < 2; ++h) {
            const int off = ((qg + h * 4) ^ (lr & 7)) * 8;
            bf16x8 af[MFR], bfr[NFR];
#pragma unroll
            for (int i = 0; i < MFR; ++i)
                af[i] = *(const bf16x8*)(As + (wr * MFR * 16 + i * 16 + lr) * 64 + off);
#pragma unroll
            for (int j = 0; j < NFR; ++j)
                bfr[j] = *(const bf16x8*)(Bs + (wc * NFR * 16 + j * 16 + lr) * 64 + off);
#pragma unroll
            for (int i = 0; i < MFR; ++i)
#pragma unroll
                for (int j = 0; j < NFR; ++j)
                    acc[i][j] = __builtin_amdgcn_mfma_f32_16x16x32_bf16(
                        af[i], bfr[j], acc[i][j], 0, 0, 0);
        }
        __syncthreads();
#pragma unroll
        for (int jj = 0; jj < NA; ++jj) aP[jj] += 64;
#pragma unroll
        for (int jj = 0; jj < NB; ++jj) bP[jj] += 64;
    }

#pragma unroll
    for (int i = 0; i < MFR; ++i) {
#pragma unroll
        for (int j = 0; j < NFR; ++j) {
            const int mm0 = tm + wr * MFR * 16 + i * 16 + (lane >> 4) * 4;
            const int nn  = tn + wc * NFR * 16 + j * 16 + (lane & 15);
#pragma unroll
            for (int r = 0; r < 4; ++r) {
                float v = acc[i][j][r] * alpha;
                if (bias) v += bias[nn];
                if (res)  v += (float)res[(long long)(mm0 + r) * ldr + nn];
                if (relu) v = fmaxf(v, 0.f);
                C[(long long)(mm0 + r) * ldc + nn] = (bf16)v;
            }
        }
    }
}

// ---------------------------------------------------------------------------
// Fused flash-style attention (R6-verified; R7 XCD-aware grid swizzle).
// ---------------------------------------------------------------------------
__global__ __launch_bounds__(256, 2)
void fused_attn_kernel(bf16* __restrict__ qkvx, const bf16* __restrict__ vt)
{
    const int flat = blockIdx.x;                     // 0..511
    const int qt = (flat >> 3) & 3;                  // q-tile
    const int z  = (flat & 7) | ((flat >> 5) << 3);  // b*4 + h
    const int b  = z >> 2, h = z & 3;

    const bf16* Qg  = qkvx + (long long)b * 512 * 3072 + h * 192;
    const bf16* Kg  = qkvx + (long long)b * 512 * 3072 + 768 + h * 192;
    const bf16* VTg = vt + (long long)z * 192 * 512;

    __shared__ __align__(16) bf16 Ks[64 * 192];    // [key][d], 24ch rows, XOR-swz
    __shared__ __align__(16) bf16 VTs[192 * 64];   // [d][key], 8ch rows, XOR-swz
    __shared__ __align__(16) bf16 Pb[4 * 32 * 64]; // per-wave [m][key], XOR-swz

    const int tid  = threadIdx.x;
    const int lane = tid & 63;
    const int wid  = tid >> 6;
    const int lr   = lane & 15;
    const int qg   = lane >> 4;
    const int m0   = qt * 128 + wid * 32;

    bf16x8 qf[2][6];
#pragma unroll
    for (int mt = 0; mt < 2; ++mt)
#pragma unroll
        for (int t = 0; t < 6; ++t)
            qf[mt][t] = *(const bf16x8*)(Qg + (long long)(m0 + mt * 16 + lr) * 3072
                                         + t * 32 + qg * 8);

    const bf16* kP[6];
    const bf16* vP[6];
#pragma unroll
    for (int i = 0; i < 6; ++i) {
        const int c = i * 256 + tid;
        const int krow = c / 24, kcc = c % 24;
        const int kgc  = (kcc & 24) | ((kcc & 7) ^ (krow & 7));
        kP[i] = Kg + (long long)krow * 3072 + kgc * 8;
        const int vrow = c >> 3, vcc = c & 7;
        const int vgc  = vcc ^ (vrow & 7);
        vP[i] = VTg + (long long)vrow * 512 + vgc * 8;
    }

    f32x4 acc[2][12];
#pragma unroll
    for (int mt = 0; mt < 2; ++mt)
#pragma unroll
        for (int dt = 0; dt < 12; ++dt) acc[mt][dt] = (f32x4){0.f, 0.f, 0.f, 0.f};
    float mrow[2][4], lrow[2][4];
#pragma unroll
    for (int mt = 0; mt < 2; ++mt)
#pragma unroll
        for (int r = 0; r < 4; ++r) { mrow[mt][r] = -3e38f; lrow[mt][r] = 0.f; }

    const float alpha = 0.0721687836f;   // 1/sqrt(192)

    for (int kt = 0; kt < 8; ++kt) {
#pragma unroll
        for (int i = 0; i < 6; ++i)
            GLD16(kP[i], Ks + (i * 256 + wid * 64) * 8);
#pragma unroll
        for (int i = 0; i < 6; ++i)
            GLD16(vP[i], VTs + (i * 256 + wid * 64) * 8);
        __syncthreads();

        f32x4 sf[2][4];
#pragma unroll
        for (int mt = 0; mt < 2; ++mt)
#pragma unroll
            for (int nt = 0; nt < 4; ++nt) sf[mt][nt] = (f32x4){0.f, 0.f, 0.f, 0.f};
#pragma unroll
        for (int nt = 0; nt < 4; ++nt) {
#pragma unroll
            for (int t = 0; t < 6; ++t) {
                const int ch = t * 4 + qg;
                const int ph = (ch & 24) | ((ch & 7) ^ (lr & 7));
                const bf16x8 kf = *(const bf16x8*)(Ks + (nt * 16 + lr) * 192 + ph * 8);
                sf[0][nt] = __builtin_amdgcn_mfma_f32_16x16x32_bf16(qf[0][t], kf, sf[0][nt], 0, 0, 0);
                sf[1][nt] = __builtin_amdgcn_mfma_f32_16x16x32_bf16(qf[1][t], kf, sf[1][nt], 0, 0, 0);
            }
        }

#pragma unroll
        for (int mt = 0; mt < 2; ++mt) {
            float mx[4], a[4], rs[4], p[4][4];
#pragma unroll
            for (int r = 0; r < 4; ++r) {
                float v0 = fmaxf(sf[mt][0][r], sf[mt][1][r]);
                float v1 = fmaxf(sf[mt][2][r], sf[mt][3][r]);
                mx[r] = fmaxf(v0, v1) * alpha;
            }
#pragma unroll
            for (int msk = 1; msk <= 8; msk <<= 1)
#pragma unroll
                for (int r = 0; r < 4; ++r) mx[r] = fmaxf(mx[r], __shfl_xor(mx[r], msk));
#pragma unroll
            for (int r = 0; r < 4; ++r) {
                const float mn = fmaxf(mrow[mt][r], mx[r]);
                a[r] = __expf(mrow[mt][r] - mn);
                mrow[mt][r] = mn;
                rs[r] = 0.f;
            }
#pragma unroll
            for (int nt = 0; nt < 4; ++nt)
#pragma unroll
                for (int r = 0; r < 4; ++r) {
                    p[nt][r] = __expf(sf[mt][nt][r] * alpha - mrow[mt][r]);
                    rs[r] += p[nt][r];
                }
#pragma unroll
            for (int msk = 1; msk <= 8; msk <<= 1)
#pragma unroll
                for (int r = 0; r < 4; ++r) rs[r] += __shfl_xor(rs[r], msk);
#pragma unroll
            for (int r = 0; r < 4; ++r) lrow[mt][r] = lrow[mt][r] * a[r] + rs[r];
#pragma unroll
            for (int dt = 0; dt < 12; ++dt)
#pragma unroll
                for (int r = 0; r < 4; ++r) acc[mt][dt][r] *= a[r];
#pragma unroll
            for (int nt = 0; nt < 4; ++nt)
#pragma unroll
                for (int r = 0; r < 4; ++r) {
                    const int row = mt * 16 + qg * 4 + r;
                    const int ph2 = (nt * 2 + (lr >> 3)) ^ (row & 7);
                    Pb[wid * 2048 + row * 64 + ph2 * 8 + (lr & 7)] = (bf16)p[nt][r];
                }
        }

        bf16x8 pf[2][2];
#pragma unroll
        for (int mt = 0; mt < 2; ++mt)
#pragma unroll
            for (int ks = 0; ks < 2; ++ks) {
                const int row = mt * 16 + lr;
                const int ph  = (ks * 4 + qg) ^ (lr & 7);
                pf[mt][ks] = *(const bf16x8*)(Pb + wid * 2048 + row * 64 + ph * 8);
            }
#pragma unroll
        for (int dt = 0; dt < 12; ++dt) {
#pragma unroll
            for (int ks = 0; ks < 2; ++ks) {
                const int ph = (ks * 4 + qg) ^ (lr & 7);
                const bf16x8 vf = *(const bf16x8*)(VTs + (dt * 16 + lr) * 64 + ph * 8);
                acc[0][dt] = __builtin_amdgcn_mfma_f32_16x16x32_bf16(pf[0][ks], vf, acc[0][dt], 0, 0, 0);
                acc[1][dt] = __builtin_amdgcn_mfma_f32_16x16x32_bf16(pf[1][ks], vf, acc[1][dt], 0, 0, 0);
            }
        }
        __syncthreads();
#pragma unroll
        for (int i = 0; i < 6; ++i) { kP[i] += 64 * 3072; vP[i] += 64; }
    }

    bf16* Og = qkvx + (long long)b * 512 * 3072 + h * 192;
#pragma unroll
    for (int mt = 0; mt < 2; ++mt) {
        float inv[4];
#pragma unroll
        for (int r = 0; r < 4; ++r) inv[r] = 1.0f / lrow[mt][r];
#pragma unroll
        for (int dt = 0; dt < 12; ++dt)
#pragma unroll
            for (int r = 0; r < 4; ++r) {
                const int row = m0 + mt * 16 + qg * 4 + r;
                Og[(long long)row * 3072 + dt * 16 + lr] = (bf16)(acc[mt][dt][r] * inv[r]);
            }
    }
}

// ---------------------------------------------------------------------------
// one-shot prep kernel: weight casts/transposes + fused bias + x+PE cast.
// ---------------------------------------------------------------------------
__device__ __forceinline__ void cast4(const float* src, bf16* dst, int i)
{
    const float4 v = *(const float4*)(src + (long long)i * 4);
    bf16x4 o;
    o[0] = (bf16)v.x; o[1] = (bf16)v.y; o[2] = (bf16)v.z; o[3] = (bf16)v.w;
    *(bf16x4*)(dst + (long long)i * 4) = o;
}

__global__ __launch_bounds__(256)
void prep_kernel(const float* __restrict__ wq, const float* __restrict__ wk,
                 const float* __restrict__ wv, const float* __restrict__ wx,
                 const float* __restrict__ inpw, const float* __restrict__ inpb,
                 const float* __restrict__ bq, const float* __restrict__ bk,
                 const float* __restrict__ bv, const float* __restrict__ bx,
                 const float* __restrict__ woutp, const float* __restrict__ wf1a,
                 const float* __restrict__ wf1b, const float* __restrict__ x,
                 bf16* __restrict__ WT3, bf16* __restrict__ INPJ,
                 bf16* __restrict__ WOUT, bf16* __restrict__ WF1A,
                 bf16* __restrict__ WF1B, bf16* __restrict__ WXD,
                 float* __restrict__ BCAT, bf16* __restrict__ XPE)
{
    const int blk = blockIdx.x;
    const int tid = threadIdx.x;
    __shared__ bf16 t[32][33];

    if (blk < 1728) {
        const int which = blk / 576, local = blk - which * 576;
        const float* src = (which == 0) ? wq : ((which == 1) ? wk : wv);
        bf16* dst = WT3 + (long long)which * 589824;
        const int r0 = (local / 24) * 32, c0 = (local % 24) * 32;
        const int tr = tid >> 5, tc = tid & 31;
#pragma unroll
        for (int k = 0; k < 4; ++k) {
            const int r = tr + k * 8;
            t[r][tc] = (bf16)src[(long long)(r0 + r) * 768 + c0 + tc];
        }
        __syncthreads();
#pragma unroll
        for (int k = 0; k < 4; ++k) {
            const int c = tr + k * 8;
            dst[(long long)(c0 + c) * 768 + r0 + tc] = t[tc][c];
        }
    } else if (blk < 3456) {
        cast4(inpw, INPJ, (blk - 1728) * 256 + tid);
    } else if (blk < 4032) {
        cast4(woutp, WOUT, (blk - 3456) * 256 + tid);
    } else if (blk < 4608) {
        cast4(wf1a, WF1A, (blk - 4032) * 256 + tid);
    } else if (blk < 5184) {
        cast4(wf1b, WF1B, (blk - 4608) * 256 + tid);
    } else if (blk < 5760) {
        cast4(wx, WXD, (blk - 5184) * 256 + tid);
    } else if (blk < 6051) {
        const int bl = blk - 5760;
        if (bl < 288) {
            const int g = tid >> 5, l = tid & 31;
            const int n = bl * 8 + g;
            const int zsec = n / 768;
            const float* bb = (zsec == 0) ? bq : ((zsec == 1) ? bk : bv);
            const float* wrow = inpw + (long long)n * 768;
            float s = 0.f;
            for (int d = l; d < 768; d += 32) s += wrow[d] * bb[d];
#pragma unroll
            for (int off = 16; off; off >>= 1) s += __shfl_xor(s, off);
            if (l == 0) BCAT[n] = inpb[n] + s;
        } else {
            const int n = (bl - 288) * 256 + tid;
            if (n < 768) BCAT[2304 + n] = bx[n];
        }
    } else {
        const int idx4 = ((blk - 6051) * 256 + tid) * 4;
        const int d    = idx4 % 768;
        const int row  = idx4 / 768;
        const int s    = row & 511;
        const float ksc = -0.034603417655076f;  // -2*log2(10000)/768
        const float4 xv = *(const float4*)(x + (long long)idx4);
        float a0 = (float)s * exp2f((float)d * ksc);
        float a1 = (float)s * exp2f((float)(d + 2) * ksc);
        float s0, c0, s1, c1;
        sincosf(a0, &s0, &c0);
        sincosf(a1, &s1, &c1);
        bf16x4 o;
        o[0] = (bf16)(xv.x + s0);
        o[1] = (bf16)(xv.y + c0);
        o[2] = (bf16)(xv.z + s1);
        o[3] = (bf16)(xv.w + c1);
        *(bf16x4*)(XPE + (long long)idx4) = o;
    }
}

// V2 [16384, cols 1536..2304 of 3072] -> VT [128][192][512]
__global__ __launch_bounds__(256)
void transpose_v_kernel(const bf16* __restrict__ qkvx, bf16* __restrict__ vt)
{
    __shared__ __align__(16) bf16 t[64][80];
    const int z  = blockIdx.z;
    const int b  = z >> 2, h = z & 3;
    const int s0 = blockIdx.y * 64;
    const int hd0 = blockIdx.x * 64;
    const int tt = threadIdx.x;
    const int sl = tt >> 2;
    const int cc = (tt & 3) * 16;
    const bf16* src = qkvx + (long long)(b * 512 + s0 + sl) * 3072 + 1536 + h * 192 + hd0 + cc;
    bf16x8 v0 = *(const bf16x8*)(src);
    bf16x8 v1 = *(const bf16x8*)(src + 8);
#pragma unroll
    for (int i = 0; i < 8; ++i) { t[sl][cc + i] = v0[i]; t[sl][cc + 8 + i] = v1[i]; }
    __syncthreads();
    const int hl = tt >> 2;
    bf16* dst = vt + ((long long)z * 192 + hd0 + hl) * 512 + s0 + cc;
    bf16x8 o0, o1;
#pragma unroll
    for (int i = 0; i < 8; ++i) { o0[i] = t[cc + i][hl]; o1[i] = t[cc + 8 + i][hl]; }
    *(bf16x8*)dst = o0;
    *(bf16x8*)(dst + 8) = o1;
}

// LayerNorm of one (pre-summed) row -> o.  192 threads, bf16x4.
__global__ __launch_bounds__(192)
void ln1_kernel(const bf16* __restrict__ a, int lda_,
                bf16* __restrict__ o, int ldo,
                const float* __restrict__ g, const float* __restrict__ be)
{
    const int row = blockIdx.x;
    const int t   = threadIdx.x;
    const int d0  = t * 4;
    const bf16x4 av = *(const bf16x4*)(a + (long long)row * lda_ + d0);
    float xv[4];
#pragma unroll
    for (int k = 0; k < 4; ++k) xv[k] = (float)av[k];
    float s1 = xv[0] + xv[1] + xv[2] + xv[3];
    float s2 = xv[0]*xv[0] + xv[1]*xv[1] + xv[2]*xv[2] + xv[3]*xv[3];
    for (int off = 32; off; off >>= 1) {
        s1 += __shfl_xor(s1, off);
        s2 += __shfl_xor(s2, off);
    }
    __shared__ float red[6];
    const int wid = t >> 6, lane = t & 63;
    if (lane == 0) { red[wid] = s1; red[3 + wid] = s2; }
    __syncthreads();
    s1 = red[0] + red[1] + red[2];
    s2 = red[3] + red[4] + red[5];
    const float mu  = s1 * (1.0f / 768.0f);
    const float var = s2 * (1.0f / 768.0f) - mu * mu;
    const float rs  = rsqrtf(var + 1e-5f);
    const float4 gv = *(const float4*)(g + d0);
    const float4 ev = *(const float4*)(be + d0);
    bf16x4 ov;
    ov[0] = (bf16)(((xv[0] - mu) * rs) * gv.x + ev.x);
    ov[1] = (bf16)(((xv[1] - mu) * rs) * gv.y + ev.y);
    ov[2] = (bf16)(((xv[2] - mu) * rs) * gv.z + ev.z);
    ov[3] = (bf16)(((xv[3] - mu) * rs) * gv.w + ev.w);
    *(bf16x4*)(o + (long long)row * ldo + d0) = ov;
}

// ---------------------------------------------------------------------------
// LN2 fused with s-sum (wave-parallel, R10-verified).
// ---------------------------------------------------------------------------
__global__ __launch_bounds__(256)
void ln2_reduce_kernel(const bf16* __restrict__ src,  /* ffn+x1, ld 3072 */
                       const float* __restrict__ g, const float* __restrict__ be,
                       float* __restrict__ partial)
{
    const int blk  = blockIdx.x;          // 0..511 (32 rows each)
    const int tid  = threadIdx.x;
    const int wid  = tid >> 6, lane = tid & 63;
    const int d0   = lane * 12;

    float gv[12], ev[12];
#pragma unroll
    for (int k = 0; k < 12; k += 4) {
        *(float4*)(gv + k) = *(const float4*)(g + d0 + k);
        *(float4*)(ev + k) = *(const float4*)(be + d0 + k);
    }
    float acc[12];
#pragma unroll
    for (int k = 0; k < 12; ++k) acc[k] = 0.f;

    for (int i = 0; i < 8; ++i) {
        const int row = blk * 32 + i * 4 + wid;
        const bf16* p = src + (long long)row * 3072 + d0;
        float xv[12];
#pragma unroll
        for (int k = 0; k < 12; k += 4) {
            const bf16x4 v = *(const bf16x4*)(p + k);
            xv[k] = (float)v[0]; xv[k+1] = (float)v[1];
            xv[k+2] = (float)v[2]; xv[k+3] = (float)v[3];
        }
        float s1 = 0.f, s2 = 0.f;
#pragma unroll
        for (int k = 0; k < 12; ++k) { s1 += xv[k]; s2 += xv[k] * xv[k]; }
        for (int off = 32; off; off >>= 1) {
            s1 += __shfl_xor(s1, off);
            s2 += __shfl_xor(s2, off);
        }
        const float mu  = s1 * (1.0f / 768.0f);
        const float var = s2 * (1.0f / 768.0f) - mu * mu;
        const float rs  = rsqrtf(var + 1e-5f);
#pragma unroll
        for (int k = 0; k < 12; ++k) acc[k] += (xv[k] - mu) * rs * gv[k] + ev[k];
    }

    __shared__ float red[4][768];
#pragma unroll
    for (int k = 0; k < 12; k += 4)
        *(float4*)(&red[wid][d0 + k]) = *(const float4*)(acc + k);
    __syncthreads();
    if (wid == 0) {
#pragma unroll
        for (int k = 0; k < 12; k += 4) {
            const float4 a0 = *(const float4*)(&red[0][d0 + k]);
            const float4 a1 = *(const float4*)(&red[1][d0 + k]);
            const float4 a2 = *(const float4*)(&red[2][d0 + k]);
            const float4 a3 = *(const float4*)(&red[3][d0 + k]);
            *(float4*)(partial + (long long)blk * 768 + d0 + k) =
                make_float4(a0.x + a1.x + a2.x + a3.x, a0.y + a1.y + a2.y + a3.y,
                            a0.z + a1.z + a2.z + a3.z, a0.w + a1.w + a2.w + a3.w);
        }
    }
}

// stage 2
__global__ __launch_bounds__(192)
void reduce_fc2_stage2_kernel(const float* __restrict__ partial, const float* __restrict__ w,
                              const float* __restrict__ bias, float* __restrict__ out)
{
    const int b = blockIdx.x, t = threadIdx.x;
    const int d0 = t * 4;
    float a[4] = {0.f, 0.f, 0.f, 0.f};
    for (int c = 0; c < 16; ++c) {
        const float4 pv = *(const float4*)(partial + (long long)(b * 16 + c) * 768 + d0);
        a[0] += pv.x; a[1] += pv.y; a[2] += pv.z; a[3] += pv.w;
    }
    __shared__ float os[10];
    if (t < 10) os[t] = 0.f;
    __syncthreads();
    for (int c = 0; c < 10; ++c) {
        const float4 wv = *(const float4*)(w + c * 768 + d0);
        float p = wv.x * a[0] + wv.y * a[1] + wv.z * a[2] + wv.w * a[3];
        for (int off = 32; off; off >>= 1) p += __shfl_xor(p, off);
        if ((t & 63) == 0) atomicAdd(&os[c], p);
    }
    __syncthreads();
    if (t < 10) out[b * 10 + t] = os[t] + bias[t];
}

// ---------------------------------------------------------------------------
// workspace layout (bytes)
// ---------------------------------------------------------------------------
static const size_t OFF_XPE  = 0;
static const size_t OFF_WCAT = OFF_XPE  + (size_t)16384 * 768 * 2;
static const size_t OFF_WT3  = OFF_WCAT + (size_t)3072 * 768 * 2;
static const size_t OFF_INPJ = OFF_WT3  + (size_t)3 * 768 * 768 * 2;
static const size_t OFF_WOUT = OFF_INPJ + (size_t)2304 * 768 * 2;
static const size_t OFF_WF1A = OFF_WOUT + (size_t)768 * 768 * 2;
static const size_t OFF_WF1B = OFF_WF1A + (size_t)768 * 768 * 2;
static const size_t OFF_BCAT = OFF_WF1B + (size_t)768 * 768 * 2;
static const size_t OFF_QKVX = OFF_BCAT + (size_t)3072 * 4;
static const size_t OFF_VT   = OFF_QKVX + (size_t)16384 * 3072 * 2;
static const size_t OFF_S    = OFF_VT   + (size_t)128 * 192 * 512 * 2;   // fc2 partials
static const size_t OFF_X1   = OFF_S    + (size_t)128 * 512 * 512 * 2;

extern "C" void kernel_launch(void* const* d_in, const int* in_sizes, int n_in,
                              void* d_out, int out_size, void* d_ws, size_t ws_size,
                              hipStream_t stream)
{
    const float* x     = (const float*)d_in[0];
    const float* wq    = (const float*)d_in[1];
    const float* bq    = (const float*)d_in[2];
    const float* wk    = (const float*)d_in[3];
    const float* bk    = (const float*)d_in[4];
    const float* wv    = (const float*)d_in[5];
    const float* bv    = (const float*)d_in[6];
    const float* wx    = (const float*)d_in[7];
    const float* bx    = (const float*)d_in[8];
    const float* inpw  = (const float*)d_in[9];
    const float* inpb  = (const float*)d_in[10];
    const float* woutp = (const float*)d_in[11];
    const float* boutp = (const float*)d_in[12];
    const float* wf1a  = (const float*)d_in[13];
    const float* bf1a  = (const float*)d_in[14];
    const float* wf1b  = (const float*)d_in[15];
    const float* bf1b  = (const float*)d_in[16];
    const float* lng   = (const float*)d_in[17];
    const float* lnb   = (const float*)d_in[18];
    const float* wfc2  = (const float*)d_in[19];
    const float* bfc2  = (const float*)d_in[20];
    float* out = (float*)d_out;

    char* ws = (char*)d_ws;
    bf16*  XPE  = (bf16*)(ws + OFF_XPE);
    bf16*  WCAT = (bf16*)(ws + OFF_WCAT);
    bf16*  WT3  = (bf16*)(ws + OFF_WT3);
    bf16*  INPJ = (bf16*)(ws + OFF_INPJ);
    bf16*  WOUT = (bf16*)(ws + OFF_WOUT);
    bf16*  WF1A = (bf16*)(ws + OFF_WF1A);
    bf16*  WF1B = (bf16*)(ws + OFF_WF1B);
    float* BCAT = (float*)(ws + OFF_BCAT);
    bf16*  QKVX = (bf16*)(ws + OFF_QKVX);
    bf16*  VT   = (bf16*)(ws + OFF_VT);
    float* PART = (float*)(ws + OFF_S);
    bf16*  X1   = (bf16*)(ws + OFF_X1);

    // ---- prep: weights + bias + x+PE (single dispatch) ----
    prep_kernel<<<18339, 256, 0, stream>>>(wq, wk, wv, wx, inpw, inpb,
                                           bq, bk, bv, bx, woutp, wf1a, wf1b, x,
                                           WT3, INPJ, WOUT, WF1A, WF1B,
                                           WCAT + (size_t)2304 * 768, BCAT, XPE);

    // W_eff[z] = in_proj_w[z] @ w{q,k,v}  (batched; no swizzle)
    gemm_nt<64, 128, 2, 4><<<dim3(6, 12, 3), 256, 0, stream>>>(
        INPJ, WT3, WCAT, nullptr, 768, 768, 768, 768,
        1, 589824, 0, 589824, 0, 589824, 0, 1.0f, 0, nullptr, 0, 0);

    // QKVX = XPE @ WCAT^T + BCAT -> [16384,3072]  (XCD-swizzled: A 1x per XCD)
    gemm_nt<128, 128, 4, 4><<<3072, 256, 0, stream>>>(
        XPE, WCAT, QKVX, BCAT, 768, 768, 768, 3072,
        1, 0, 0, 0, 0, 0, 0, 1.0f, 0, nullptr, 0, 24);

    transpose_v_kernel<<<dim3(3, 8, 128), 256, 0, stream>>>(QKVX, VT);

    // fused attention (XCD-swizzled grid): Q2 region overwritten with ctx
    fused_attn_kernel<<<512, 256, 0, stream>>>(QKVX, VT);

    // attn_out + XR residual -> K2 region  (XCD-swizzled)
    gemm_nt<64, 128, 2, 4><<<1536, 256, 0, stream>>>(
        QKVX, WOUT, QKVX + 768, boutp, 768, 3072, 768, 3072,
        1, 0, 0, 0, 0, 0, 0, 1.0f, 0, QKVX + 2304, 3072, 6);

    // x1 = LN(attn_out + XR)
    ln1_kernel<<<16384, 192, 0, stream>>>(QKVX + 768, 3072, X1, 768, lng, lnb);

    // h1 = relu(x1 @ fc1a^T + b) -> V2 region  (XCD-swizzled)
    gemm_nt<64, 128, 2, 4><<<1536, 256, 0, stream>>>(
        X1, WF1A, QKVX + 1536, bf1a, 768, 768, 768, 3072,
        1, 0, 0, 0, 0, 0, 0, 1.0f, 1, nullptr, 0, 6);

    // ffn + x1 residual -> XR region  (XCD-swizzled)
    gemm_nt<64, 128, 2, 4><<<1536, 256, 0, stream>>>(
        QKVX + 1536, WF1B, QKVX + 2304, bf1b, 768, 3072, 768, 3072,
        1, 0, 0, 0, 0, 0, 0, 1.0f, 0, X1, 768, 6);

    // LN2 + s-sum fused (x2 never materialized)
    ln2_reduce_kernel<<<512, 256, 0, stream>>>(QKVX + 2304, lng, lnb, PART);

    // out = partial-sum @ fc2^T + b
    reduce_fc2_stage2_kernel<<<32, 192, 0, stream>>>(PART, wfc2, bfc2, out);
}

// Round 13
// 496.364 us; speedup vs baseline: 1.0458x; 1.0248x over previous
//
#include <hip/hip_runtime.h>
#include <hip/hip_bf16.h>

typedef __bf16 bf16;
typedef __bf16 bf16x8 __attribute__((ext_vector_type(8)));
typedef __bf16 bf16x4 __attribute__((ext_vector_type(4)));
typedef __bf16 bf16x2 __attribute__((ext_vector_type(2)));
typedef float  f32x4  __attribute__((ext_vector_type(4)));

#define GLD16(g, l) __builtin_amdgcn_global_load_lds(                        \
    (const __attribute__((address_space(1))) void*)(g),                      \
    (__attribute__((address_space(3))) void*)(l), 16, 0, 0)

// ---------------------------------------------------------------------------
// NT GEMM: C[m,n] = alpha * sum_k A[m,k]*B[n,k] (+ bias[n]) (+ relu) (+ res)
// BK=64; swizzled LDS (conflict-free, R2); pointer-bump staging (R3).
// Tile rule (R7/R8): BM=128 throughput-bound, BM=64 latency-bound short grids.
// R12 ERRATUM: XCD tile-swizzle regressed — default 2D grid already maps
// n-tile -> XCD x%8 (24%8==0), partitioning B per-XCD; A 8x re-fetch is
// L3-absorbed.  Swizzle removed.
// ---------------------------------------------------------------------------
template<int BM, int BN, int MFR, int NFR>
__global__ __launch_bounds__(256, 3)
void gemm_nt(const bf16* __restrict__ A, const bf16* __restrict__ B,
             bf16* __restrict__ C, const float* __restrict__ bias,
             int K, int lda, int ldb, int ldc,
             int inner,
             long long aOut, long long aIn,
             long long bOut, long long bIn,
             long long cOut, long long cIn,
             float alpha, int relu,
             const bf16* __restrict__ res, int ldr)
{
    const int z  = blockIdx.z;
    const int zo = z / inner;
    const int zi = z - zo * inner;
    A += (long long)zo * aOut + (long long)zi * aIn;
    B += (long long)zo * bOut + (long long)zi * bIn;
    C += (long long)zo * cOut + (long long)zi * cIn;

    const int tm = blockIdx.y * BM;
    const int tn = blockIdx.x * BN;

    __shared__ __align__(16) bf16 smem[(BM + BN) * 64];
    bf16* As = smem;
    bf16* Bs = smem + BM * 64;

    const int tid  = threadIdx.x;
    const int lane = tid & 63;
    const int wid  = tid >> 6;
    const int wr   = wid >> 1;
    const int wc   = wid & 1;

    f32x4 acc[MFR][NFR];
#pragma unroll
    for (int i = 0; i < MFR; ++i)
#pragma unroll
        for (int j = 0; j < NFR; ++j) acc[i][j] = (f32x4){0.f, 0.f, 0.f, 0.f};

    const int srow = lane >> 3;
    const int gch8 = ((lane & 7) ^ srow) * 8;

    const int NA = BM / 32;
    const int NB = BN / 32;

    const bf16* aP[NA];
#pragma unroll
    for (int jj = 0; jj < NA; ++jj) {
        const int R0 = (wid * NA + jj) * 8;
        aP[jj] = A + (long long)(tm + R0 + srow) * lda + gch8;
    }
    const bf16* bP[NB];
#pragma unroll
    for (int jj = 0; jj < NB; ++jj) {
        const int R0 = (wid * NB + jj) * 8;
        bP[jj] = B + (long long)(tn + R0 + srow) * ldb + gch8;
    }

    const int lr = lane & 15;
    const int qg = lane >> 4;

    for (int kt = 0; kt < K; kt += 64) {
#pragma unroll
        for (int jj = 0; jj < NA; ++jj)
            GLD16(aP[jj], As + (wid * NA + jj) * 512);
#pragma unroll
        for (int jj = 0; jj < NB; ++jj)
            GLD16(bP[jj], Bs + (wid * NB + jj) * 512);
        __syncthreads();

#pragma unroll
        for (int h = 0; h < 2; ++h) {
            const int off = ((qg + h * 4) ^ (lr & 7)) * 8;
            bf16x8 af[MFR], bfr[NFR];
#pragma unroll
            for (int i = 0; i < MFR; ++i)
                af[i] = *(const bf16x8*)(As + (wr * MFR * 16 + i * 16 + lr) * 64 + off);
#pragma unroll
            for (int j = 0; j < NFR; ++j)
                bfr[j] = *(const bf16x8*)(Bs + (wc * NFR * 16 + j * 16 + lr) * 64 + off);
#pragma unroll
            for (int i = 0; i < MFR; ++i)
#pragma unroll
                for (int j = 0; j < NFR; ++j)
                    acc[i][j] = __builtin_amdgcn_mfma_f32_16x16x32_bf16(
                        af[i], bfr[j], acc[i][j], 0, 0, 0);
        }
        __syncthreads();
#pragma unroll
        for (int jj = 0; jj < NA; ++jj) aP[jj] += 64;
#pragma unroll
        for (int jj = 0; jj < NB; ++jj) bP[jj] += 64;
    }

#pragma unroll
    for (int i = 0; i < MFR; ++i) {
#pragma unroll
        for (int j = 0; j < NFR; ++j) {
            const int mm0 = tm + wr * MFR * 16 + i * 16 + (lane >> 4) * 4;
            const int nn  = tn + wc * NFR * 16 + j * 16 + (lane & 15);
#pragma unroll
            for (int r = 0; r < 4; ++r) {
                float v = acc[i][j][r] * alpha;
                if (bias) v += bias[nn];
                if (res)  v += (float)res[(long long)(mm0 + r) * ldr + nn];
                if (relu) v = fmaxf(v, 0.f);
                C[(long long)(mm0 + r) * ldc + nn] = (bf16)v;
            }
        }
    }
}

// ---------------------------------------------------------------------------
// Fused flash-style attention (R6-verified; R7 XCD-aware grid swizzle).
// R13: V^T staging fused in — each thread reads 2 adjacent V rows' d-chunk
// (2x16B global) and writes 8 packed bf16x2 LDS stores into the swizzled
// VTs layout (phys chunk = (key>>3)^(d&7), matching the PV read side).
// Write banks: ((kp>>2)^(d&7))*4 + (kp&3) covers all 32 banks once per
// 32-lane group -> conflict-free.  Kills the transpose_v dispatch and the
// 50 MB VT HBM round-trip.
// ---------------------------------------------------------------------------
__global__ __launch_bounds__(256, 2)
void fused_attn_kernel(bf16* __restrict__ qkvx)
{
    const int flat = blockIdx.x;                     // 0..511
    const int qt = (flat >> 3) & 3;                  // q-tile
    const int z  = (flat & 7) | ((flat >> 5) << 3);  // b*4 + h
    const int b  = z >> 2, h = z & 3;

    const bf16* Qg = qkvx + (long long)b * 512 * 3072 + h * 192;
    const bf16* Kg = Qg + 768;
    const bf16* Vg = Qg + 1536;                      // [s][d] rows, ld 3072

    __shared__ __align__(16) bf16 Ks[64 * 192];    // [key][d], 24ch rows, XOR-swz
    __shared__ __align__(16) bf16 VTs[192 * 64];   // [d][key], 8ch rows, XOR-swz
    __shared__ __align__(16) bf16 Pb[4 * 32 * 64]; // per-wave [m][key], XOR-swz

    const int tid  = threadIdx.x;
    const int lane = tid & 63;
    const int wid  = tid >> 6;
    const int lr   = lane & 15;
    const int qg   = lane >> 4;
    const int m0   = qt * 128 + wid * 32;

    bf16x8 qf[2][6];
#pragma unroll
    for (int mt = 0; mt < 2; ++mt)
#pragma unroll
        for (int t = 0; t < 6; ++t)
            qf[mt][t] = *(const bf16x8*)(Qg + (long long)(m0 + mt * 16 + lr) * 3072
                                         + t * 32 + qg * 8);

    const bf16* kP[6];
#pragma unroll
    for (int i = 0; i < 6; ++i) {
        const int c = i * 256 + tid;
        const int krow = c / 24, kcc = c % 24;
        const int kgc  = (kcc & 24) | ((kcc & 7) ^ (krow & 7));
        kP[i] = Kg + (long long)krow * 3072 + kgc * 8;
    }
    // V transpose staging indices (fixed per thread)
    const int vkp = tid & 31;        // key pair 0..31 -> keys 2vkp, 2vkp+1
    const int vdc = tid >> 5;        // d-chunk base (+8 per i)

    f32x4 acc[2][12];
#pragma unroll
    for (int mt = 0; mt < 2; ++mt)
#pragma unroll
        for (int dt = 0; dt < 12; ++dt) acc[mt][dt] = (f32x4){0.f, 0.f, 0.f, 0.f};
    float mrow[2][4], lrow[2][4];
#pragma unroll
    for (int mt = 0; mt < 2; ++mt)
#pragma unroll
        for (int r = 0; r < 4; ++r) { mrow[mt][r] = -3e38f; lrow[mt][r] = 0.f; }

    const float alpha = 0.0721687836f;   // 1/sqrt(192)

    for (int kt = 0; kt < 8; ++kt) {
#pragma unroll
        for (int i = 0; i < 6; ++i)
            GLD16(kP[i], Ks + (i * 256 + wid * 64) * 8);
        // ---- V^T staging: 2 rows x 8 d, packed bf16x2 stores ----
#pragma unroll
        for (int i = 0; i < 3; ++i) {
            const int dc = vdc + i * 8;                  // 0..23
            const bf16* p = Vg + (long long)(2 * vkp) * 3072 + dc * 8;
            const bf16x8 v0 = *(const bf16x8*)(p);
            const bf16x8 v1 = *(const bf16x8*)(p + 3072);
#pragma unroll
            for (int j = 0; j < 8; ++j) {
                const int d = dc * 8 + j;
                bf16x2 pk; pk[0] = v0[j]; pk[1] = v1[j];
                *(bf16x2*)(VTs + d * 64 + ((vkp >> 2) ^ (d & 7)) * 8
                           + 2 * (vkp & 3)) = pk;
            }
        }
        __syncthreads();

        f32x4 sf[2][4];
#pragma unroll
        for (int mt = 0; mt < 2; ++mt)
#pragma unroll
            for (int nt = 0; nt < 4; ++nt) sf[mt][nt] = (f32x4){0.f, 0.f, 0.f, 0.f};
#pragma unroll
        for (int nt = 0; nt < 4; ++nt) {
#pragma unroll
            for (int t = 0; t < 6; ++t) {
                const int ch = t * 4 + qg;
                const int ph = (ch & 24) | ((ch & 7) ^ (lr & 7));
                const bf16x8 kf = *(const bf16x8*)(Ks + (nt * 16 + lr) * 192 + ph * 8);
                sf[0][nt] = __builtin_amdgcn_mfma_f32_16x16x32_bf16(qf[0][t], kf, sf[0][nt], 0, 0, 0);
                sf[1][nt] = __builtin_amdgcn_mfma_f32_16x16x32_bf16(qf[1][t], kf, sf[1][nt], 0, 0, 0);
            }
        }

#pragma unroll
        for (int mt = 0; mt < 2; ++mt) {
            float mx[4], a[4], rs[4], p[4][4];
#pragma unroll
            for (int r = 0; r < 4; ++r) {
                float v0 = fmaxf(sf[mt][0][r], sf[mt][1][r]);
                float v1 = fmaxf(sf[mt][2][r], sf[mt][3][r]);
                mx[r] = fmaxf(v0, v1) * alpha;
            }
#pragma unroll
            for (int msk = 1; msk <= 8; msk <<= 1)
#pragma unroll
                for (int r = 0; r < 4; ++r) mx[r] = fmaxf(mx[r], __shfl_xor(mx[r], msk));
#pragma unroll
            for (int r = 0; r < 4; ++r) {
                const float mn = fmaxf(mrow[mt][r], mx[r]);
                a[r] = __expf(mrow[mt][r] - mn);
                mrow[mt][r] = mn;
                rs[r] = 0.f;
            }
#pragma unroll
            for (int nt = 0; nt < 4; ++nt)
#pragma unroll
                for (int r = 0; r < 4; ++r) {
                    p[nt][r] = __expf(sf[mt][nt][r] * alpha - mrow[mt][r]);
                    rs[r] += p[nt][r];
                }
#pragma unroll
            for (int msk = 1; msk <= 8; msk <<= 1)
#pragma unroll
                for (int r = 0; r < 4; ++r) rs[r] += __shfl_xor(rs[r], msk);
#pragma unroll
            for (int r = 0; r < 4; ++r) lrow[mt][r] = lrow[mt][r] * a[r] + rs[r];
#pragma unroll
            for (int dt = 0; dt < 12; ++dt)
#pragma unroll
                for (int r = 0; r < 4; ++r) acc[mt][dt][r] *= a[r];
#pragma unroll
            for (int nt = 0; nt < 4; ++nt)
#pragma unroll
                for (int r = 0; r < 4; ++r) {
                    const int row = mt * 16 + qg * 4 + r;
                    const int ph2 = (nt * 2 + (lr >> 3)) ^ (row & 7);
                    Pb[wid * 2048 + row * 64 + ph2 * 8 + (lr & 7)] = (bf16)p[nt][r];
                }
        }

        bf16x8 pf[2][2];
#pragma unroll
        for (int mt = 0; mt < 2; ++mt)
#pragma unroll
            for (int ks = 0; ks < 2; ++ks) {
                const int row = mt * 16 + lr;
                const int ph  = (ks * 4 + qg) ^ (lr & 7);
                pf[mt][ks] = *(const bf16x8*)(Pb + wid * 2048 + row * 64 + ph * 8);
            }
#pragma unroll
        for (int dt = 0; dt < 12; ++dt) {
#pragma unroll
            for (int ks = 0; ks < 2; ++ks) {
                const int ph = (ks * 4 + qg) ^ (lr & 7);
                const bf16x8 vf = *(const bf16x8*)(VTs + (dt * 16 + lr) * 64 + ph * 8);
                acc[0][dt] = __builtin_amdgcn_mfma_f32_16x16x32_bf16(pf[0][ks], vf, acc[0][dt], 0, 0, 0);
                acc[1][dt] = __builtin_amdgcn_mfma_f32_16x16x32_bf16(pf[1][ks], vf, acc[1][dt], 0, 0, 0);
            }
        }
        __syncthreads();
#pragma unroll
        for (int i = 0; i < 6; ++i) kP[i] += 64 * 3072;
        Vg += 64 * 3072;
    }

    bf16* Og = qkvx + (long long)b * 512 * 3072 + h * 192;
#pragma unroll
    for (int mt = 0; mt < 2; ++mt) {
        float inv[4];
#pragma unroll
        for (int r = 0; r < 4; ++r) inv[r] = 1.0f / lrow[mt][r];
#pragma unroll
        for (int dt = 0; dt < 12; ++dt)
#pragma unroll
            for (int r = 0; r < 4; ++r) {
                const int row = m0 + mt * 16 + qg * 4 + r;
                Og[(long long)row * 3072 + dt * 16 + lr] = (bf16)(acc[mt][dt][r] * inv[r]);
            }
    }
}

// ---------------------------------------------------------------------------
// one-shot prep kernel: weight casts/transposes + fused bias + x+PE cast.
// ---------------------------------------------------------------------------
__device__ __forceinline__ void cast4(const float* src, bf16* dst, int i)
{
    const float4 v = *(const float4*)(src + (long long)i * 4);
    bf16x4 o;
    o[0] = (bf16)v.x; o[1] = (bf16)v.y; o[2] = (bf16)v.z; o[3] = (bf16)v.w;
    *(bf16x4*)(dst + (long long)i * 4) = o;
}

__global__ __launch_bounds__(256)
void prep_kernel(const float* __restrict__ wq, const float* __restrict__ wk,
                 const float* __restrict__ wv, const float* __restrict__ wx,
                 const float* __restrict__ inpw, const float* __restrict__ inpb,
                 const float* __restrict__ bq, const float* __restrict__ bk,
                 const float* __restrict__ bv, const float* __restrict__ bx,
                 const float* __restrict__ woutp, const float* __restrict__ wf1a,
                 const float* __restrict__ wf1b, const float* __restrict__ x,
                 bf16* __restrict__ WT3, bf16* __restrict__ INPJ,
                 bf16* __restrict__ WOUT, bf16* __restrict__ WF1A,
                 bf16* __restrict__ WF1B, bf16* __restrict__ WXD,
                 float* __restrict__ BCAT, bf16* __restrict__ XPE)
{
    const int blk = blockIdx.x;
    const int tid = threadIdx.x;
    __shared__ bf16 t[32][33];

    if (blk < 1728) {
        const int which = blk / 576, local = blk - which * 576;
        const float* src = (which == 0) ? wq : ((which == 1) ? wk : wv);
        bf16* dst = WT3 + (long long)which * 589824;
        const int r0 = (local / 24) * 32, c0 = (local % 24) * 32;
        const int tr = tid >> 5, tc = tid & 31;
#pragma unroll
        for (int k = 0; k < 4; ++k) {
            const int r = tr + k * 8;
            t[r][tc] = (bf16)src[(long long)(r0 + r) * 768 + c0 + tc];
        }
        __syncthreads();
#pragma unroll
        for (int k = 0; k < 4; ++k) {
            const int c = tr + k * 8;
            dst[(long long)(c0 + c) * 768 + r0 + tc] = t[tc][c];
        }
    } else if (blk < 3456) {
        cast4(inpw, INPJ, (blk - 1728) * 256 + tid);
    } else if (blk < 4032) {
        cast4(woutp, WOUT, (blk - 3456) * 256 + tid);
    } else if (blk < 4608) {
        cast4(wf1a, WF1A, (blk - 4032) * 256 + tid);
    } else if (blk < 5184) {
        cast4(wf1b, WF1B, (blk - 4608) * 256 + tid);
    } else if (blk < 5760) {
        cast4(wx, WXD, (blk - 5184) * 256 + tid);
    } else if (blk < 6051) {
        const int bl = blk - 5760;
        if (bl < 288) {
            const int g = tid >> 5, l = tid & 31;
            const int n = bl * 8 + g;
            const int zsec = n / 768;
            const float* bb = (zsec == 0) ? bq : ((zsec == 1) ? bk : bv);
            const float* wrow = inpw + (long long)n * 768;
            float s = 0.f;
            for (int d = l; d < 768; d += 32) s += wrow[d] * bb[d];
#pragma unroll
            for (int off = 16; off; off >>= 1) s += __shfl_xor(s, off);
            if (l == 0) BCAT[n] = inpb[n] + s;
        } else {
            const int n = (bl - 288) * 256 + tid;
            if (n < 768) BCAT[2304 + n] = bx[n];
        }
    } else {
        const int idx4 = ((blk - 6051) * 256 + tid) * 4;
        const int d    = idx4 % 768;
        const int row  = idx4 / 768;
        const int s    = row & 511;
        const float ksc = -0.034603417655076f;  // -2*log2(10000)/768
        const float4 xv = *(const float4*)(x + (long long)idx4);
        float a0 = (float)s * exp2f((float)d * ksc);
        float a1 = (float)s * exp2f((float)(d + 2) * ksc);
        float s0, c0, s1, c1;
        sincosf(a0, &s0, &c0);
        sincosf(a1, &s1, &c1);
        bf16x4 o;
        o[0] = (bf16)(xv.x + s0);
        o[1] = (bf16)(xv.y + c0);
        o[2] = (bf16)(xv.z + s1);
        o[3] = (bf16)(xv.w + c1);
        *(bf16x4*)(XPE + (long long)idx4) = o;
    }
}

// LayerNorm of one (pre-summed) row -> o.  192 threads, bf16x4.
__global__ __launch_bounds__(192)
void ln1_kernel(const bf16* __restrict__ a, int lda_,
                bf16* __restrict__ o, int ldo,
                const float* __restrict__ g, const float* __restrict__ be)
{
    const int row = blockIdx.x;
    const int t   = threadIdx.x;
    const int d0  = t * 4;
    const bf16x4 av = *(const bf16x4*)(a + (long long)row * lda_ + d0);
    float xv[4];
#pragma unroll
    for (int k = 0; k < 4; ++k) xv[k] = (float)av[k];
    float s1 = xv[0] + xv[1] + xv[2] + xv[3];
    float s2 = xv[0]*xv[0] + xv[1]*xv[1] + xv[2]*xv[2] + xv[3]*xv[3];
    for (int off = 32; off; off >>= 1) {
        s1 += __shfl_xor(s1, off);
        s2 += __shfl_xor(s2, off);
    }
    __shared__ float red[6];
    const int wid = t >> 6, lane = t & 63;
    if (lane == 0) { red[wid] = s1; red[3 + wid] = s2; }
    __syncthreads();
    s1 = red[0] + red[1] + red[2];
    s2 = red[3] + red[4] + red[5];
    const float mu  = s1 * (1.0f / 768.0f);
    const float var = s2 * (1.0f / 768.0f) - mu * mu;
    const float rs  = rsqrtf(var + 1e-5f);
    const float4 gv = *(const float4*)(g + d0);
    const float4 ev = *(const float4*)(be + d0);
    bf16x4 ov;
    ov[0] = (bf16)(((xv[0] - mu) * rs) * gv.x + ev.x);
    ov[1] = (bf16)(((xv[1] - mu) * rs) * gv.y + ev.y);
    ov[2] = (bf16)(((xv[2] - mu) * rs) * gv.z + ev.z);
    ov[3] = (bf16)(((xv[3] - mu) * rs) * gv.w + ev.w);
    *(bf16x4*)(o + (long long)row * ldo + d0) = ov;
}

// ---------------------------------------------------------------------------
// LN2 fused with s-sum (wave-parallel, R10-verified).
// ---------------------------------------------------------------------------
__global__ __launch_bounds__(256)
void ln2_reduce_kernel(const bf16* __restrict__ src,  /* ffn+x1, ld 3072 */
                       const float* __restrict__ g, const float* __restrict__ be,
                       float* __restrict__ partial)
{
    const int blk  = blockIdx.x;          // 0..511 (32 rows each)
    const int tid  = threadIdx.x;
    const int wid  = tid >> 6, lane = tid & 63;
    const int d0   = lane * 12;

    float gv[12], ev[12];
#pragma unroll
    for (int k = 0; k < 12; k += 4) {
        *(float4*)(gv + k) = *(const float4*)(g + d0 + k);
        *(float4*)(ev + k) = *(const float4*)(be + d0 + k);
    }
    float acc[12];
#pragma unroll
    for (int k = 0; k < 12; ++k) acc[k] = 0.f;

    for (int i = 0; i < 8; ++i) {
        const int row = blk * 32 + i * 4 + wid;
        const bf16* p = src + (long long)row * 3072 + d0;
        float xv[12];
#pragma unroll
        for (int k = 0; k < 12; k += 4) {
            const bf16x4 v = *(const bf16x4*)(p + k);
            xv[k] = (float)v[0]; xv[k+1] = (float)v[1];
            xv[k+2] = (float)v[2]; xv[k+3] = (float)v[3];
        }
        float s1 = 0.f, s2 = 0.f;
#pragma unroll
        for (int k = 0; k < 12; ++k) { s1 += xv[k]; s2 += xv[k] * xv[k]; }
        for (int off = 32; off; off >>= 1) {
            s1 += __shfl_xor(s1, off);
            s2 += __shfl_xor(s2, off);
        }
        const float mu  = s1 * (1.0f / 768.0f);
        const float var = s2 * (1.0f / 768.0f) - mu * mu;
        const float rs  = rsqrtf(var + 1e-5f);
#pragma unroll
        for (int k = 0; k < 12; ++k) acc[k] += (xv[k] - mu) * rs * gv[k] + ev[k];
    }

    __shared__ float red[4][768];
#pragma unroll
    for (int k = 0; k < 12; k += 4)
        *(float4*)(&red[wid][d0 + k]) = *(const float4*)(acc + k);
    __syncthreads();
    if (wid == 0) {
#pragma unroll
        for (int k = 0; k < 12; k += 4) {
            const float4 a0 = *(const float4*)(&red[0][d0 + k]);
            const float4 a1 = *(const float4*)(&red[1][d0 + k]);
            const float4 a2 = *(const float4*)(&red[2][d0 + k]);
            const float4 a3 = *(const float4*)(&red[3][d0 + k]);
            *(float4*)(partial + (long long)blk * 768 + d0 + k) =
                make_float4(a0.x + a1.x + a2.x + a3.x, a0.y + a1.y + a2.y + a3.y,
                            a0.z + a1.z + a2.z + a3.z, a0.w + a1.w + a2.w + a3.w);
        }
    }
}

// stage 2
__global__ __launch_bounds__(192)
void reduce_fc2_stage2_kernel(const float* __restrict__ partial, const float* __restrict__ w,
                              const float* __restrict__ bias, float* __restrict__ out)
{
    const int b = blockIdx.x, t = threadIdx.x;
    const int d0 = t * 4;
    float a[4] = {0.f, 0.f, 0.f, 0.f};
    for (int c = 0; c < 16; ++c) {
        const float4 pv = *(const float4*)(partial + (long long)(b * 16 + c) * 768 + d0);
        a[0] += pv.x; a[1] += pv.y; a[2] += pv.z; a[3] += pv.w;
    }
    __shared__ float os[10];
    if (t < 10) os[t] = 0.f;
    __syncthreads();
    for (int c = 0; c < 10; ++c) {
        const float4 wv = *(const float4*)(w + c * 768 + d0);
        float p = wv.x * a[0] + wv.y * a[1] + wv.z * a[2] + wv.w * a[3];
        for (int off = 32; off; off >>= 1) p += __shfl_xor(p, off);
        if ((t & 63) == 0) atomicAdd(&os[c], p);
    }
    __syncthreads();
    if (t < 10) out[b * 10 + t] = os[t] + bias[t];
}

// ---------------------------------------------------------------------------
// workspace layout (bytes)
// ---------------------------------------------------------------------------
static const size_t OFF_XPE  = 0;
static const size_t OFF_WCAT = OFF_XPE  + (size_t)16384 * 768 * 2;
static const size_t OFF_WT3  = OFF_WCAT + (size_t)3072 * 768 * 2;
static const size_t OFF_INPJ = OFF_WT3  + (size_t)3 * 768 * 768 * 2;
static const size_t OFF_WOUT = OFF_INPJ + (size_t)2304 * 768 * 2;
static const size_t OFF_WF1A = OFF_WOUT + (size_t)768 * 768 * 2;
static const size_t OFF_WF1B = OFF_WF1A + (size_t)768 * 768 * 2;
static const size_t OFF_BCAT = OFF_WF1B + (size_t)768 * 768 * 2;
static const size_t OFF_QKVX = OFF_BCAT + (size_t)3072 * 4;
static const size_t OFF_VT   = OFF_QKVX + (size_t)16384 * 3072 * 2;   // unused (R13)
static const size_t OFF_S    = OFF_VT   + (size_t)128 * 192 * 512 * 2; // fc2 partials
static const size_t OFF_X1   = OFF_S    + (size_t)128 * 512 * 512 * 2;

extern "C" void kernel_launch(void* const* d_in, const int* in_sizes, int n_in,
                              void* d_out, int out_size, void* d_ws, size_t ws_size,
                              hipStream_t stream)
{
    const float* x     = (const float*)d_in[0];
    const float* wq    = (const float*)d_in[1];
    const float* bq    = (const float*)d_in[2];
    const float* wk    = (const float*)d_in[3];
    const float* bk    = (const float*)d_in[4];
    const float* wv    = (const float*)d_in[5];
    const float* bv    = (const float*)d_in[6];
    const float* wx    = (const float*)d_in[7];
    const float* bx    = (const float*)d_in[8];
    const float* inpw  = (const float*)d_in[9];
    const float* inpb  = (const float*)d_in[10];
    const float* woutp = (const float*)d_in[11];
    const float* boutp = (const float*)d_in[12];
    const float* wf1a  = (const float*)d_in[13];
    const float* bf1a  = (const float*)d_in[14];
    const float* wf1b  = (const float*)d_in[15];
    const float* bf1b  = (const float*)d_in[16];
    const float* lng   = (const float*)d_in[17];
    const float* lnb   = (const float*)d_in[18];
    const float* wfc2  = (const float*)d_in[19];
    const float* bfc2  = (const float*)d_in[20];
    float* out = (float*)d_out;

    char* ws = (char*)d_ws;
    bf16*  XPE  = (bf16*)(ws + OFF_XPE);
    bf16*  WCAT = (bf16*)(ws + OFF_WCAT);
    bf16*  WT3  = (bf16*)(ws + OFF_WT3);
    bf16*  INPJ = (bf16*)(ws + OFF_INPJ);
    bf16*  WOUT = (bf16*)(ws + OFF_WOUT);
    bf16*  WF1A = (bf16*)(ws + OFF_WF1A);
    bf16*  WF1B = (bf16*)(ws + OFF_WF1B);
    float* BCAT = (float*)(ws + OFF_BCAT);
    bf16*  QKVX = (bf16*)(ws + OFF_QKVX);
    float* PART = (float*)(ws + OFF_S);
    bf16*  X1   = (bf16*)(ws + OFF_X1);

    // ---- prep: weights + bias + x+PE (single dispatch) ----
    prep_kernel<<<18339, 256, 0, stream>>>(wq, wk, wv, wx, inpw, inpb,
                                           bq, bk, bv, bx, woutp, wf1a, wf1b, x,
                                           WT3, INPJ, WOUT, WF1A, WF1B,
                                           WCAT + (size_t)2304 * 768, BCAT, XPE);

    // W_eff[z] = in_proj_w[z] @ w{q,k,v}
    gemm_nt<64, 128, 2, 4><<<dim3(6, 12, 3), 256, 0, stream>>>(
        INPJ, WT3, WCAT, nullptr, 768, 768, 768, 768,
        1, 589824, 0, 589824, 0, 589824, 0, 1.0f, 0, nullptr, 0);

    // QKVX = XPE @ WCAT^T + BCAT -> [16384,3072]  (BM=128: throughput-bound)
    gemm_nt<128, 128, 4, 4><<<dim3(24, 128, 1), 256, 0, stream>>>(
        XPE, WCAT, QKVX, BCAT, 768, 768, 768, 3072,
        1, 0, 0, 0, 0, 0, 0, 1.0f, 0, nullptr, 0);

    // fused attention (XCD-swizzled grid, V^T staged in-kernel):
    // Q2 region overwritten with ctx
    fused_attn_kernel<<<512, 256, 0, stream>>>(QKVX);

    // attn_out + XR residual -> K2 region  (BM=64: latency-bound)
    gemm_nt<64, 128, 2, 4><<<dim3(6, 256, 1), 256, 0, stream>>>(
        QKVX, WOUT, QKVX + 768, boutp, 768, 3072, 768, 3072,
        1, 0, 0, 0, 0, 0, 0, 1.0f, 0, QKVX + 2304, 3072);

    // x1 = LN(attn_out + XR)
    ln1_kernel<<<16384, 192, 0, stream>>>(QKVX + 768, 3072, X1, 768, lng, lnb);

    // h1 = relu(x1 @ fc1a^T + b) -> V2 region
    gemm_nt<64, 128, 2, 4><<<dim3(6, 256, 1), 256, 0, stream>>>(
        X1, WF1A, QKVX + 1536, bf1a, 768, 768, 768, 3072,
        1, 0, 0, 0, 0, 0, 0, 1.0f, 1, nullptr, 0);

    // ffn + x1 residual -> XR region
    gemm_nt<64, 128, 2, 4><<<dim3(6, 256, 1), 256, 0, stream>>>(
        QKVX + 1536, WF1B, QKVX + 2304, bf1b, 768, 3072, 768, 3072,
        1, 0, 0, 0, 0, 0, 0, 1.0f, 0, X1, 768);

    // LN2 + s-sum fused (x2 never materialized)
    ln2_reduce_kernel<<<512, 256, 0, stream>>>(QKVX + 2304, lng, lnb, PART);

    // out = partial-sum @ fc2^T + b
    reduce_fc2_stage2_kernel<<<32, 192, 0, stream>>>(PART, wfc2, bfc2, out);
}